// Round 4
// baseline (7000.170 us; speedup 1.0000x reference)
//
#include <hip/hip_runtime.h>

typedef __attribute__((ext_vector_type(4))) float f32x4;

// All-f32, MFMA-free, workspace-free correctness anchor.
// Block = 32 rows x 256 threads (4 waves). Thread (w = t&63, ng = t>>6) computes
// 8 rows (n = ng*8+i) of output column w for every GEMM.
//
// LDS planes P[8][32][64] f32:
//   phase A:  P0 = s, P1..P3 = v_x,v_y,v_z       (x1 tile, de-interleaved)
//   phase B:  P4 = s0raw, P5..P7 = v0raw_xyz     (stage-1 lin0 outputs)
//   phase C:  P0 = mA, P1 = mB, P2 = mD          (overwrite dead X planes)
//   phase E:  P0 = mCx, P1 = mCy, P2 = mCz
// cst[32][6]: e0, e1x, e1y, e1z, kp, ksc

__global__ __launch_bounds__(256, 2) void fused_f32(
    const float* __restrict__ x1, const float* __restrict__ edge,
    const float* __restrict__ tp, const float* __restrict__ node,
    const float* __restrict__ Wsc_s, const float* __restrict__ Wlin0_s,
    const float* __restrict__ Wsc_v, const float* __restrict__ Wlin0_v,
    const float* __restrict__ WA, const float* __restrict__ WD,
    const float* __restrict__ WB, const float* __restrict__ WC,
    float* __restrict__ out) {
  __shared__ float P[8][32][64];
  __shared__ float cst[32][6];
  const int t = threadIdx.x;
  const int R0 = blockIdx.x * 32;

  // ---- phase A: stage x1 tile; row constants ----
  for (int idx = t; idx < 32 * 256; idx += 256) {
    int r = idx >> 8, c = idx & 255;
    float v = x1[(size_t)(R0 + r) * 256 + c];
    if (c < 64) P[0][r][c] = v;
    else { int q = c - 64; int u = q / 3; int m = q - 3 * u; P[1 + m][r][u] = v; }
  }
  if (t < 32) {
    f32x4 e = *(const f32x4*)(edge + (size_t)(R0 + t) * 4);
    float a = node[R0 + t];
    cst[t][0] = e[0]; cst[t][1] = e[1]; cst[t][2] = e[2]; cst[t][3] = e[3];
    cst[t][4] = 0.125f * 0.08838834764831845f * a * a;  // kp = INV_SQRT_MUL*INV_SQRT_2MUL*a^2
    cst[t][5] = 0.125f * a;                             // ksc = INV_SQRT_MUL*a
  }
  __syncthreads();

  const int w = t & 63;
  const int ng = t >> 6;  // rows n = ng*8 + i

  // acc[i] += sum_u IN[ng*8+i][u] * W[u][w]   (IN broadcast from LDS, W coalesced global)
  auto gemm = [&](const float (*__restrict__ IN)[64], const float* __restrict__ W,
                  float (&acc)[8]) {
    for (int uc = 0; uc < 16; ++uc) {
      float w0 = W[(uc * 4 + 0) * 64 + w];
      float w1 = W[(uc * 4 + 1) * 64 + w];
      float w2 = W[(uc * 4 + 2) * 64 + w];
      float w3 = W[(uc * 4 + 3) * 64 + w];
#pragma unroll
      for (int i = 0; i < 8; ++i) {
        f32x4 in4 = *(const f32x4*)(&IN[ng * 8 + i][uc * 4]);
        acc[i] += in4[0] * w0;
        acc[i] += in4[1] * w1;
        acc[i] += in4[2] * w2;
        acc[i] += in4[3] * w3;
      }
    }
  };

  // ---- phase B: stage-1 GEMMs ----
  float scs[8] = {0,0,0,0,0,0,0,0};
  float scv[3][8] = {{0}};
  {
    float t8[8] = {0,0,0,0,0,0,0,0};
    gemm(P[0], Wsc_s, scs);
    gemm(P[0], Wlin0_s, t8);
#pragma unroll
    for (int i = 0; i < 8; ++i) P[4][ng * 8 + i][w] = t8[i];
#pragma unroll
    for (int m = 0; m < 3; ++m) {
      float u8[8] = {0,0,0,0,0,0,0,0};
      gemm(P[1 + m], Wsc_v, scv[m]);
      gemm(P[1 + m], Wlin0_v, u8);
#pragma unroll
      for (int i = 0; i < 8; ++i) P[5 + m][ng * 8 + i][w] = u8[i];
    }
  }
  __syncthreads();

  // ---- phase C: mids mA/mB/mD -> P0/P1/P2 ----
#pragma unroll
  for (int i = 0; i < 8; ++i) {
    int n = ng * 8 + i;
    float e0 = cst[n][0], e1x = cst[n][1], e1y = cst[n][2], e1z = cst[n][3];
    float s0 = P[4][n][w];
    float vx = P[5][n][w], vy = P[6][n][w], vz = P[7][n][w];
    const float* tr = tp + (size_t)(R0 + n) * 256;
    float wa = tr[w], wb = tr[64 + w], wd = tr[192 + w];
    P[0][n][w] = wa * s0 * e0;
    P[1][n][w] = wb * s0;
    P[2][n][w] = wd * (vx * e1x + vy * e1y + vz * e1z) * 0.5773502691896258f;
  }
  __syncthreads();

  // ---- phase D: gAD = mA@WA + mD@WD ; gB = mB@WB ----
  float gAD[8] = {0,0,0,0,0,0,0,0};
  float gB[8] = {0,0,0,0,0,0,0,0};
  gemm(P[0], WA, gAD);
  gemm(P[2], WD, gAD);
  gemm(P[1], WB, gB);
  __syncthreads();

  // ---- phase E: mids mC_xyz -> P0/P1/P2 ----
#pragma unroll
  for (int i = 0; i < 8; ++i) {
    int n = ng * 8 + i;
    float e0 = cst[n][0];
    float vx = P[5][n][w], vy = P[6][n][w], vz = P[7][n][w];
    float wc = tp[(size_t)(R0 + n) * 256 + 128 + w];
    P[0][n][w] = wc * vx * e0;
    P[1][n][w] = wc * vy * e0;
    P[2][n][w] = wc * vz * e0;
  }
  __syncthreads();

  // ---- phase F: gC_m = mC_m @ WC ----
  float gC[3][8] = {{0}};
#pragma unroll
  for (int m = 0; m < 3; ++m) gemm(P[m], WC, gC[m]);

  // ---- epilogue ----
#pragma unroll
  for (int i = 0; i < 8; ++i) {
    int n = ng * 8 + i;
    float e1x = cst[n][1], e1y = cst[n][2], e1z = cst[n][3];
    float kp = cst[n][4], ksc = cst[n][5];
    float* orow = out + (size_t)(R0 + n) * 256;
    orow[w] = kp * gAD[i] + ksc * scs[i];
    float vx = kp * (e1x * gB[i] + gC[0][i]) + ksc * scv[0][i];
    float vy = kp * (e1y * gB[i] + gC[1][i]) + ksc * scv[1][i];
    float vz = kp * (e1z * gB[i] + gC[2][i]) + ksc * scv[2][i];
    float* vp = orow + 64 + 3 * w;
    vp[0] = vx; vp[1] = vy; vp[2] = vz;
  }
}

extern "C" void kernel_launch(void* const* d_in, const int* in_sizes, int n_in,
                              void* d_out, int out_size, void* d_ws, size_t ws_size,
                              hipStream_t stream) {
  const float* x1   = (const float*)d_in[0];
  const float* edge = (const float*)d_in[1];
  const float* tp   = (const float*)d_in[2];
  const float* node = (const float*)d_in[3];
  int n = in_sizes[0] / 256;  // 200000

  fused_f32<<<n / 32, 256, 0, stream>>>(
      x1, edge, tp, node,
      (const float*)d_in[6],  // W_sc_s
      (const float*)d_in[4],  // W_lin0_s
      (const float*)d_in[7],  // W_sc_v
      (const float*)d_in[5],  // W_lin0_v
      (const float*)d_in[8],  // W_lin_A
      (const float*)d_in[9],  // W_lin_D
      (const float*)d_in[10], // W_lin_B
      (const float*)d_in[11], // W_lin_C
      (float*)d_out);
}

// Round 6
// 813.492 us; speedup vs baseline: 8.6051x; 8.6051x over previous
//
#include <hip/hip_runtime.h>

typedef __attribute__((ext_vector_type(4))) float f32x4;
typedef __attribute__((ext_vector_type(8))) short bf16x8;

#define MFMA(a, b, c) __builtin_amdgcn_mfma_f32_16x16x32_bf16(a, b, c, 0, 0, 0)

static __device__ __forceinline__ short rnebf(float x) {
  union { float f; unsigned u; } v; v.f = x;
  return (short)((v.u + 0x7FFFu + ((v.u >> 16) & 1u)) >> 16);
}
static __device__ __forceinline__ float bf2f(short h) {
  union { unsigned u; float f; } v; v.u = ((unsigned)(unsigned short)h) << 16;
  return v.f;
}
static __device__ __forceinline__ void split(float x, short& h, short& l) {
  h = rnebf(x);
  l = rnebf(x - bf2f(h));
}

// ---- R5 machinery under test ----
static __device__ __forceinline__ void stageW(const float* __restrict__ Wm,
                                              short* __restrict__ Wh, short* __restrict__ Wl,
                                              int t) {
#pragma unroll
  for (int q = 0; q < 2; ++q) {
    int fl = q * 256 + t;
    int lane = fl & 63, fragid = fl >> 6;
    int ct = fragid >> 1, kh = fragid & 1;
    int col = ct * 16 + (lane & 15);
    int k0 = kh * 32 + ((lane >> 4) << 3);
    bf16x8 vh, vl;
#pragma unroll
    for (int j = 0; j < 8; ++j) {
      short h, l;
      split(Wm[(size_t)(k0 + j) * 64 + col], h, l);
      vh[j] = h; vl[j] = l;
    }
    *(bf16x8*)(Wh + fl * 8) = vh;
    *(bf16x8*)(Wl + fl * 8) = vl;
  }
}

static __device__ __forceinline__ f32x4 gemm3(const bf16x8 (&ah)[2], const bf16x8 (&al)[2],
                                              const short* __restrict__ Wh,
                                              const short* __restrict__ Wl,
                                              int ct, int lane, f32x4 acc) {
#pragma unroll
  for (int kh = 0; kh < 2; ++kh) {
    bf16x8 bh = *(const bf16x8*)(Wh + (ct * 2 + kh) * 512 + lane * 8);
    bf16x8 bl = *(const bf16x8*)(Wl + (ct * 2 + kh) * 512 + lane * 8);
    acc = MFMA(ah[kh], bh, acc);
    acc = MFMA(al[kh], bh, acc);
    acc = MFMA(ah[kh], bl, acc);
  }
  return acc;
}

static __device__ __forceinline__ void ldM(const short* __restrict__ M, int ph, int arow,
                                           int lane, bf16x8 (&ah)[2], bf16x8 (&al)[2]) {
  int swz = (arow & 7) << 4;
#pragma unroll
  for (int kh = 0; kh < 2; ++kh) {
    int ab = (arow * 128 + kh * 64 + ((lane >> 4) << 4)) ^ swz;
    ah[kh] = *(const bf16x8*)((const char*)M + ph * 8192 + ab);
    al[kh] = *(const bf16x8*)((const char*)M + (ph + 1) * 8192 + ab);
  }
}
static __device__ __forceinline__ void stM(short* __restrict__ M, int p, int n, int w, float x) {
  short h, l;
  split(x, h, l);
  int ab = (n * 128 + w * 2) ^ ((n & 7) << 4);
  *(short*)((char*)M + p * 8192 + ab) = h;
  *(short*)((char*)M + (p + 1) * 8192 + ab) = l;
}

// ---- test patterns (bf16-exact integers) ----
static __device__ __forceinline__ float Af(int r, int k) { return (float)(((r * 7 + k * 3) & 15) - 8); }
static __device__ __forceinline__ float Bfp(int k, int c) { return (float)(((k * 5 + c * 11) & 15) - 8); }
static __device__ __forceinline__ float Vf(int n, int w) { return (float)(((n * 5 + w * 3) % 31) - 15); }

// ---- despilled f32 GEMM: 8 rows per thread, by-value accumulators ----
struct A8 { f32x4 x, y; };

static __device__ __forceinline__ A8 gemmv(const float (*__restrict__ IN)[64],
                                           const float* __restrict__ W,
                                           int ng, int w, A8 acc) {
#pragma unroll 4
  for (int uc = 0; uc < 16; ++uc) {
    float w0 = W[(uc * 4 + 0) * 64 + w];
    float w1 = W[(uc * 4 + 1) * 64 + w];
    float w2 = W[(uc * 4 + 2) * 64 + w];
    float w3 = W[(uc * 4 + 3) * 64 + w];
#pragma unroll
    for (int i = 0; i < 4; ++i) {
      f32x4 in4 = *(const f32x4*)(&IN[ng * 8 + i][uc * 4]);
      acc.x[i] += in4[0] * w0 + in4[1] * w1 + in4[2] * w2 + in4[3] * w3;
    }
#pragma unroll
    for (int i = 0; i < 4; ++i) {
      f32x4 in4 = *(const f32x4*)(&IN[ng * 8 + 4 + i][uc * 4]);
      acc.y[i] += in4[0] * w0 + in4[1] * w1 + in4[2] * w2 + in4[3] * w3;
    }
  }
  return acc;
}

__global__ __launch_bounds__(256, 2) void fused_diag(
    const float* __restrict__ x1, const float* __restrict__ edge,
    const float* __restrict__ tp, const float* __restrict__ node,
    const float* __restrict__ Wsc_s, const float* __restrict__ Wlin0_s,
    const float* __restrict__ Wsc_v, const float* __restrict__ Wlin0_v,
    const float* __restrict__ WA, const float* __restrict__ WD,
    const float* __restrict__ WB, const float* __restrict__ WC,
    float* __restrict__ out) {
  __shared__ float P[8][32][64];
  __shared__ float cst[32][6];
  const int t = threadIdx.x;
  const int R0 = blockIdx.x * 32;
  int fails = 0;

  // ================= self-test battery (block 0 only; block-local barriers) ===============
  if (blockIdx.x == 0) {
    const int l = t & 63;
    const int lwid = t >> 6;
    const f32x4 z = {0.f, 0.f, 0.f, 0.f};
    short* tWh = (short*)&P[0][0][0];            // 8 KB
    short* tWl = tWh + 4096;                     // 8 KB
    short* tM  = tWl + 4096;                     // 16 KB (2 planes)

    // --- bit0/1/4/5: register-only MFMA layout probe ---
    {
      bf16x8 ta, tb;
#pragma unroll
      for (int j = 0; j < 8; ++j) {
        ta[j] = rnebf(Af(l & 15, (l >> 4) * 8 + j));
        tb[j] = rnebf(Bfp((l >> 4) * 8 + j, l & 15));
      }
      f32x4 d = MFMA(ta, tb, z);
      int f1 = 0, p2 = 0, p3 = 0, p4 = 0;
#pragma unroll
      for (int reg = 0; reg < 4; ++reg) {
        float e1 = 0, e2 = 0, e3 = 0, e4 = 0;
        int r1 = (l >> 4) * 4 + reg, c1 = l & 15;
        int r3 = (l >> 4) + 4 * reg;
        for (int k = 0; k < 32; ++k) {
          e1 += Af(r1, k) * Bfp(k, c1);
          e2 += Af(c1, k) * Bfp(k, r1);
          e3 += Af(r3, k) * Bfp(k, c1);
          e4 += Af(c1, k) * Bfp(k, r3);
        }
        f1 |= (d[reg] != e1);
        p2 += (d[reg] == e2);
        p3 += (d[reg] == e3);
        p4 += (d[reg] == e4);
      }
      if (__any(f1)) fails |= 1;
      if (!__any(p2 != 4)) fails |= 2;
      if (!__any(p3 != 4)) fails |= 16;
      if (!__any(p4 != 4)) fails |= 32;
    }

    // --- bit2: stageW + gemm3 vs VALU dot of real global weights ---
    {
      stageW(Wsc_s, tWh, tWl, t);
      __syncthreads();
      bf16x8 tah[2], tal[2];
#pragma unroll
      for (int kh = 0; kh < 2; ++kh) {
#pragma unroll
        for (int j = 0; j < 8; ++j) {
          tah[kh][j] = rnebf(Af(l & 15, kh * 32 + (l >> 4) * 8 + j));
          tal[kh][j] = 0;
        }
      }
      int f2 = 0;
#pragma unroll
      for (int ct = 0; ct < 4; ++ct) {
        f32x4 dm = gemm3(tah, tal, tWh, tWl, ct, l, z);
        int cc = ct * 16 + (l & 15);
#pragma unroll
        for (int reg = 0; reg < 4; ++reg) {
          int rr = (l >> 4) * 4 + reg;
          float ex = 0.f;
          for (int k = 0; k < 64; ++k) ex += Af(rr, k) * Wsc_s[k * 64 + cc];
          float df = dm[reg] - ex;
          if (df < 0) df = -df;
          float mag = ex < 0 ? -ex : ex;
          if (df > 0.05f + 1e-3f * mag) f2 = 1;
        }
      }
      if (__any(f2)) fails |= 4;
      __syncthreads();
    }

    // --- bit3: stM/ldM swizzled round-trip (exact) ---
    {
      int r0t = lwid * 16, lg = l >> 4;
#pragma unroll
      for (int reg = 0; reg < 4; ++reg) {
        int n = r0t + (lg << 2) + reg;
#pragma unroll
        for (int ct = 0; ct < 4; ++ct) {
          int w = ct * 16 + (l & 15);
          stM(tM, 0, n, w, Vf(n, w));
        }
      }
      __syncthreads();
      int arow = r0t + (l & 15);
      bf16x8 ah[2], al[2];
      ldM(tM, 0, arow, l, ah, al);
      int f3 = 0;
#pragma unroll
      for (int kh = 0; kh < 2; ++kh) {
#pragma unroll
        for (int j = 0; j < 8; ++j) {
          int k = kh * 32 + (l >> 4) * 8 + j;
          if (bf2f(ah[kh][j]) != Vf(arow, k)) f3 = 1;
          if (bf2f(al[kh][j]) != 0.f) f3 = 1;
        }
      }
      if (__any(f3)) fails |= 8;
      __syncthreads();
    }
  }
  __syncthreads();

  // ================= real compute: R4's proven f32 pipeline, despilled =================
  for (int idx = t; idx < 32 * 256; idx += 256) {
    int r = idx >> 8, c = idx & 255;
    float v = x1[(size_t)(R0 + r) * 256 + c];
    if (c < 64) P[0][r][c] = v;
    else { int q = c - 64; int u = q / 3; int m = q - 3 * u; P[1 + m][r][u] = v; }
  }
  if (t < 32) {
    f32x4 e = *(const f32x4*)(edge + (size_t)(R0 + t) * 4);
    float a = node[R0 + t];
    cst[t][0] = e[0]; cst[t][1] = e[1]; cst[t][2] = e[2]; cst[t][3] = e[3];
    cst[t][4] = 0.125f * 0.08838834764831845f * a * a;
    cst[t][5] = 0.125f * a;
  }
  __syncthreads();

  const int w = t & 63;
  const int ng = t >> 6;
  A8 zz; zz.x = (f32x4){0,0,0,0}; zz.y = (f32x4){0,0,0,0};

  // phase B: stage-1 GEMMs
  A8 scs = gemmv(P[0], Wsc_s, ng, w, zz);
  {
    A8 t8 = gemmv(P[0], Wlin0_s, ng, w, zz);
#pragma unroll
    for (int i = 0; i < 4; ++i) { P[4][ng * 8 + i][w] = t8.x[i]; P[4][ng * 8 + 4 + i][w] = t8.y[i]; }
  }
  A8 scv0 = gemmv(P[1], Wsc_v, ng, w, zz);
  A8 scv1 = gemmv(P[2], Wsc_v, ng, w, zz);
  A8 scv2 = gemmv(P[3], Wsc_v, ng, w, zz);
  {
    A8 u0 = gemmv(P[1], Wlin0_v, ng, w, zz);
#pragma unroll
    for (int i = 0; i < 4; ++i) { P[5][ng * 8 + i][w] = u0.x[i]; P[5][ng * 8 + 4 + i][w] = u0.y[i]; }
    A8 u1 = gemmv(P[2], Wlin0_v, ng, w, zz);
#pragma unroll
    for (int i = 0; i < 4; ++i) { P[6][ng * 8 + i][w] = u1.x[i]; P[6][ng * 8 + 4 + i][w] = u1.y[i]; }
    A8 u2 = gemmv(P[3], Wlin0_v, ng, w, zz);
#pragma unroll
    for (int i = 0; i < 4; ++i) { P[7][ng * 8 + i][w] = u2.x[i]; P[7][ng * 8 + 4 + i][w] = u2.y[i]; }
  }
  __syncthreads();

  // phase C: mids mA/mB/mD -> P0/P1/P2
#pragma unroll
  for (int i = 0; i < 8; ++i) {
    int n = ng * 8 + i;
    float e0 = cst[n][0], e1x = cst[n][1], e1y = cst[n][2], e1z = cst[n][3];
    float s0 = P[4][n][w];
    float vx = P[5][n][w], vy = P[6][n][w], vz = P[7][n][w];
    const float* tr = tp + (size_t)(R0 + n) * 256;
    P[0][n][w] = tr[w] * s0 * e0;
    P[1][n][w] = tr[64 + w] * s0;
    P[2][n][w] = tr[192 + w] * (vx * e1x + vy * e1y + vz * e1z) * 0.5773502691896258f;
  }
  __syncthreads();

  // phase D
  A8 gAD = gemmv(P[0], WA, ng, w, zz);
  gAD = gemmv(P[2], WD, ng, w, gAD);
  A8 gB = gemmv(P[1], WB, ng, w, zz);
  __syncthreads();

  // phase E: mC -> P0/P1/P2
#pragma unroll
  for (int i = 0; i < 8; ++i) {
    int n = ng * 8 + i;
    float e0 = cst[n][0];
    float vx = P[5][n][w], vy = P[6][n][w], vz = P[7][n][w];
    float wc = tp[(size_t)(R0 + n) * 256 + 128 + w];
    P[0][n][w] = wc * vx * e0;
    P[1][n][w] = wc * vy * e0;
    P[2][n][w] = wc * vz * e0;
  }
  __syncthreads();

  // phase F
  A8 gC0 = gemmv(P[0], WC, ng, w, zz);
  A8 gC1 = gemmv(P[1], WC, ng, w, zz);
  A8 gC2 = gemmv(P[2], WC, ng, w, zz);

  // epilogue
#pragma unroll
  for (int i = 0; i < 8; ++i) {
    int n = ng * 8 + i;
    float e1x = cst[n][1], e1y = cst[n][2], e1z = cst[n][3];
    float kp = cst[n][4], ksc = cst[n][5];
    float gad = i < 4 ? gAD.x[i & 3] : gAD.y[i & 3];
    float gb  = i < 4 ? gB.x[i & 3]  : gB.y[i & 3];
    float g0  = i < 4 ? gC0.x[i & 3] : gC0.y[i & 3];
    float g1  = i < 4 ? gC1.x[i & 3] : gC1.y[i & 3];
    float g2  = i < 4 ? gC2.x[i & 3] : gC2.y[i & 3];
    float ss  = i < 4 ? scs.x[i & 3] : scs.y[i & 3];
    float sv0 = i < 4 ? scv0.x[i & 3] : scv0.y[i & 3];
    float sv1 = i < 4 ? scv1.x[i & 3] : scv1.y[i & 3];
    float sv2 = i < 4 ? scv2.x[i & 3] : scv2.y[i & 3];
    float* orow = out + (size_t)(R0 + n) * 256;
    orow[w] = kp * gad + ksc * ss;
    float vx = kp * (e1x * gb + g0) + ksc * sv0;
    float vy = kp * (e1y * gb + g1) + ksc * sv1;
    float vz = kp * (e1z * gb + g2) + ksc * sv2;
    float* vp = orow + 64 + 3 * w;
    vp[0] = vx; vp[1] = vy; vp[2] = vz;
  }

  // ---- diagnostic encode: absmax = 8192 + 256*failmask (decodable) ----
  __syncthreads();
  if (blockIdx.x == 0 && t == 0 && (fails & 13)) {
    out[0] = 8192.0f + 256.0f * (float)fails;
  }
}

extern "C" void kernel_launch(void* const* d_in, const int* in_sizes, int n_in,
                              void* d_out, int out_size, void* d_ws, size_t ws_size,
                              hipStream_t stream) {
  const float* x1   = (const float*)d_in[0];
  const float* edge = (const float*)d_in[1];
  const float* tp   = (const float*)d_in[2];
  const float* node = (const float*)d_in[3];
  int n = in_sizes[0] / 256;

  fused_diag<<<n / 32, 256, 0, stream>>>(
      x1, edge, tp, node,
      (const float*)d_in[6],  // W_sc_s
      (const float*)d_in[4],  // W_lin0_s
      (const float*)d_in[7],  // W_sc_v
      (const float*)d_in[5],  // W_lin0_v
      (const float*)d_in[8],  // W_lin_A
      (const float*)d_in[9],  // W_lin_D
      (const float*)d_in[10], // W_lin_B
      (const float*)d_in[11], // W_lin_C
      (float*)d_out);
}